// Round 1
// baseline (302.878 us; speedup 1.0000x reference)
//
#include <hip/hip_runtime.h>
#include <stdint.h>

typedef short s16x8 __attribute__((ext_vector_type(8)));
typedef unsigned short u16x8 __attribute__((ext_vector_type(8)));
typedef float f32x4 __attribute__((ext_vector_type(4)));

__device__ __forceinline__ unsigned short f2bf(float f) {
    union { float f; uint32_t u; } v; v.f = f;
    uint32_t r = v.u + 0x7FFFu + ((v.u >> 16) & 1u);
    return (unsigned short)(r >> 16);
}

__device__ __forceinline__ s16x8 ldfrag(const unsigned short* p) {
    return *(const s16x8*)p;
}

// ---------------- weight quantization ----------------
// p_c: [256,128,3,3,7] f32 -> wq: [9][256][128] bf16 (as ushort)
// Replicates ref: norm over last dim, logits = 10*(v/norm), argmax (first max),
// w = q_level[idx]. q_level values are exact in bf16.
__global__ void quant_k(const float* __restrict__ pc,
                        const float* __restrict__ ql,
                        unsigned short* __restrict__ wq) {
    int p = blockIdx.x * 256 + threadIdx.x;     // p = (kpos*256 + o)*128 + c
    if (p >= 9 * 256 * 128) return;
    int c = p & 127;
    int o = (p >> 7) & 255;
    int kpos = p >> 15;
    const float* v = pc + ((size_t)((o * 128 + c) * 9 + kpos) * 7);
    float vv[7];
    float s = 0.f;
#pragma unroll
    for (int j = 0; j < 7; ++j) { vv[j] = v[j]; s += vv[j] * vv[j]; }
    float norm = sqrtf(s);
    float best = 10.0f * (vv[0] / norm);
    int bi = 0;
#pragma unroll
    for (int j = 1; j < 7; ++j) {
        float t = 10.0f * (vv[j] / norm);
        if (t > best) { best = t; bi = j; }
    }
    wq[p] = f2bf(ql[bi]);
}

// ---------------- implicit-GEMM conv ----------------
// x: [32][128][56][56] f32, wq: [9][256][128] bf16, out: [32][256][56][56] f32
// Block: 64 output channels x (4 rows x 56 cols) spatial, one n.
// 4 waves in 2(o) x 2(s) grid; wave tile 32 o x 112 s; MFMA 16x16x32 bf16.
__global__ __launch_bounds__(256) void conv_k(const float* __restrict__ x,
                                              const unsigned short* __restrict__ wq,
                                              float* __restrict__ out) {
    // xs: [r=6][col=58][c=32 pad->40]   (halo rows/cols, zero-padded)
    // wl: [kk=9][o=64][c=32 pad->40]
    __shared__ __align__(16) unsigned short xs[6 * 58 * 40];
    __shared__ __align__(16) unsigned short wl[9 * 64 * 40];

    const int tid = threadIdx.x;
    const int h0 = blockIdx.x * 4;
    const int n  = blockIdx.y;
    const int o0 = blockIdx.z * 64;
    const int lane = tid & 63;
    const int wave = tid >> 6;
    const int wo  = wave >> 1;   // 0..1 : o half
    const int wsd = wave & 1;    // 0..1 : spatial half
    const int l16 = lane & 15;
    const int kgrp = lane >> 4;  // 0..3

    int xb[7]; int rr[7]; int wwv[7];
#pragma unroll
    for (int f = 0; f < 7; ++f) {
        int s = wsd * 112 + f * 16 + l16;   // block-local spatial 0..223
        int r = s / 56;
        int w = s - r * 56;
        rr[f] = r; wwv[f] = w;
        xb[f] = (r * 58 + w) * 40 + kgrp * 8;   // col index for kw=0 is w (w_in = w-1)
    }
    const int wa = (wo * 32 + l16) * 40 + kgrp * 8;

    f32x4 acc[2][7];
#pragma unroll
    for (int a = 0; a < 2; ++a)
#pragma unroll
        for (int f = 0; f < 7; ++f) acc[a][f] = (f32x4){0.f, 0.f, 0.f, 0.f};

    for (int c0 = 0; c0 < 128; c0 += 32) {
        // ---- stage x chunk: c0..c0+31, rows h0-1..h0+4, cols -1..56 ----
        for (int e = tid; e < 32 * 6 * 58; e += 256) {
            int c = e / 348;            // 348 = 6*58
            int rem = e - c * 348;
            int r = rem / 58;
            int col = rem - r * 58;
            int h = h0 - 1 + r;
            int w = col - 1;
            float val = 0.f;
            if ((unsigned)h < 56u && (unsigned)w < 56u)
                val = x[((n * 128 + c0 + c) * 56 + h) * 56 + w];
            xs[(r * 58 + col) * 40 + c] = f2bf(val);
        }
        // ---- stage weights: all 9 taps for this c-chunk ----
#pragma unroll
        for (int it = 0; it < 9; ++it) {
            int v = tid + it * 256;             // 0..2303
            int cseg = v & 3;
            int o = (v >> 2) & 63;
            int kk = v >> 8;
            u16x8 dat = *(const u16x8*)(wq + (kk * 256 + o0 + o) * 128 + c0 + cseg * 8);
            *(u16x8*)(&wl[(kk * 64 + o) * 40 + cseg * 8]) = dat;
        }
        __syncthreads();
#pragma unroll
        for (int kk = 0; kk < 9; ++kk) {
            const int kh = kk / 3;
            const int kw = kk - kh * 3;
            s16x8 a0 = ldfrag(&wl[kk * 2560 + wa]);
            s16x8 a1 = ldfrag(&wl[kk * 2560 + wa + 640]);
            const int xoff = (kh * 58 + kw) * 40;
#pragma unroll
            for (int f = 0; f < 7; ++f) {
                s16x8 b = ldfrag(&xs[xb[f] + xoff]);
                acc[0][f] = __builtin_amdgcn_mfma_f32_16x16x32_bf16(a0, b, acc[0][f], 0, 0, 0);
                acc[1][f] = __builtin_amdgcn_mfma_f32_16x16x32_bf16(a1, b, acc[1][f], 0, 0, 0);
            }
        }
        __syncthreads();
    }

    // ---- epilogue: D row = o offset (kgrp*4 + j), col = spatial (l16) ----
#pragma unroll
    for (int of = 0; of < 2; ++of) {
        int ob = o0 + wo * 32 + of * 16 + kgrp * 4;
#pragma unroll
        for (int f = 0; f < 7; ++f) {
            int h = h0 + rr[f];
            float* dst = out + ((n * 256 + ob) * 56 + h) * 56 + wwv[f];
#pragma unroll
            for (int j = 0; j < 4; ++j) dst[j * 3136] = acc[of][f][j];
        }
    }
}

extern "C" void kernel_launch(void* const* d_in, const int* in_sizes, int n_in,
                              void* d_out, int out_size, void* d_ws, size_t ws_size,
                              hipStream_t stream) {
    const float* x   = (const float*)d_in[0];
    const float* pc  = (const float*)d_in[1];
    const float* ql  = (const float*)d_in[2];
    float* out = (float*)d_out;
    unsigned short* wq = (unsigned short*)d_ws;   // 9*256*128 bf16 = 589,824 B

    quant_k<<<dim3(9 * 256 * 128 / 256), dim3(256), 0, stream>>>(pc, ql, wq);
    conv_k<<<dim3(14, 32, 4), dim3(256), 0, stream>>>(x, wq, out);
}

// Round 2
// 141.353 us; speedup vs baseline: 2.1427x; 2.1427x over previous
//
#include <hip/hip_runtime.h>
#include <stdint.h>

typedef short s16x8 __attribute__((ext_vector_type(8)));
typedef unsigned short u16x8 __attribute__((ext_vector_type(8)));
typedef float f32x4 __attribute__((ext_vector_type(4)));
typedef uint32_t u32x4 __attribute__((ext_vector_type(4)));

#define XPAD_ELEMS (32 * 58 * 58 * 128)
#define XPAD_BYTES ((size_t)XPAD_ELEMS * 2)
#define WQ_BYTES ((size_t)9 * 256 * 128 * 2)

static __device__ __forceinline__ unsigned short f2bf(float f) {
    union { float f; uint32_t u; } v; v.f = f;
    uint32_t r = v.u + 0x7FFFu + ((v.u >> 16) & 1u);
    return (unsigned short)(r >> 16);
}

static __device__ __forceinline__ s16x8 ldfrag(const unsigned short* p) {
    return *(const s16x8*)p;
}

// async 16B global -> LDS (linear: wave-uniform LDS base + lane*16)
static __device__ __forceinline__ void gload16(const unsigned short* g, unsigned short* l) {
    __builtin_amdgcn_global_load_lds(
        (const __attribute__((address_space(1))) uint32_t*)g,
        (__attribute__((address_space(3))) uint32_t*)l, 16, 0, 0);
}

// ---------------- weight quantization ----------------
// p_c: [256,128,3,3,7] f32 -> wq: [9][256][128] bf16
__global__ void quant_k(const float* __restrict__ pc,
                        const float* __restrict__ ql,
                        unsigned short* __restrict__ wq) {
    int p = blockIdx.x * 256 + threadIdx.x;
    if (p >= 9 * 256 * 128) return;
    int c = p & 127;
    int o = (p >> 7) & 255;
    int kpos = p >> 15;
    const float* v = pc + ((size_t)((o * 128 + c) * 9 + kpos) * 7);
    float vv[7];
    float s = 0.f;
#pragma unroll
    for (int j = 0; j < 7; ++j) { vv[j] = v[j]; s += vv[j] * vv[j]; }
    float norm = sqrtf(s);
    float best = 10.0f * (vv[0] / norm);
    int bi = 0;
#pragma unroll
    for (int j = 1; j < 7; ++j) {
        float t = 10.0f * (vv[j] / norm);
        if (t > best) { best = t; bi = j; }
    }
    wq[p] = f2bf(ql[bi]);
}

// ---------------- zero-fill padded x buffer ----------------
__global__ void zero_k(uint32_t* __restrict__ p, int n4) {
    u32x4 z = (u32x4){0u, 0u, 0u, 0u};
    for (int i = blockIdx.x * blockDim.x + threadIdx.x; i < n4; i += gridDim.x * blockDim.x)
        ((u32x4*)p)[i] = z;
}

// ---------------- x: NCHW f32 -> padded NHWC bf16 ----------------
// xpad: [32][58][58][128], interior only (borders pre-zeroed)
__global__ __launch_bounds__(256) void xform_k(const float* __restrict__ x,
                                               unsigned short* __restrict__ xpad) {
    __shared__ float tile[64 * 57];
    const int h = blockIdx.x;          // 0..55
    const int n = blockIdx.y;
    const int c0 = blockIdx.z * 64;    // 0 or 64
    const int t = threadIdx.x;
    if (t < 224) {
        int c4 = t / 56;
        int w = t - c4 * 56;
        const float* src = x + ((size_t)(n * 128 + c0 + c4) * 56 + h) * 56 + w;
#pragma unroll
        for (int cc = 0; cc < 16; ++cc)
            tile[(cc * 4 + c4) * 57 + w] = src[(size_t)cc * 4 * 3136];
    }
    __syncthreads();
    int c = t & 63, wg = t >> 6;
    unsigned short* dst = xpad + ((size_t)(n * 58 + h + 1) * 58 + 1) * 128 + c0 + c;
#pragma unroll
    for (int ww = 0; ww < 14; ++ww) {
        int w = ww * 4 + wg;
        dst[(size_t)w * 128] = f2bf(tile[c * 57 + w]);
    }
}

// ---------------- implicit-GEMM conv (DMA-staged) ----------------
// xpad: [32][58][58][128] bf16, wq: [9][256][128] bf16, out: [32][256][56][56] f32
// LDS xs: chunk (cseg 0..3)[pos = r*58+col, 348] of 16B (8 c's at one position)
// LDS wl: chunk (cseg 0..3)[kk*64+o, 576] of 16B
__global__ __launch_bounds__(256) void conv2_k(const unsigned short* __restrict__ xpad,
                                               const unsigned short* __restrict__ wq,
                                               float* __restrict__ out) {
    __shared__ __align__(16) unsigned short xs[1408 * 8];   // 22.5 KB (1392 used)
    __shared__ __align__(16) unsigned short wl[2304 * 8];   // 36.9 KB

    const int tid = threadIdx.x;
    const int h0 = blockIdx.x * 4;
    const int n = blockIdx.y;
    const int o0 = blockIdx.z * 64;
    const int lane = tid & 63;
    const int wave = tid >> 6;
    const int wo = wave >> 1;    // o half
    const int wsd = wave & 1;    // spatial half
    const int l16 = lane & 15;
    const int kgrp = lane >> 4;

    // ---- precompute staging source offsets (independent of c0) ----
    int offx[6]; bool vx[6];
#pragma unroll
    for (int i = 0; i < 6; ++i) {
        int ci = i * 256 + tid;
        vx[i] = ci < 1392;
        int ce = vx[i] ? ci : 0;
        int cseg = ce / 348;
        int pos = ce - cseg * 348;
        int r = pos / 58;
        int col = pos - r * 58;
        offx[i] = ((n * 58 + h0 + r) * 58 + col) * 128 + cseg * 8;
    }
    int offw[9];
#pragma unroll
    for (int i = 0; i < 9; ++i) {
        int ci = i * 256 + tid;
        int cseg = ci / 576;
        int rem = ci - cseg * 576;
        int kk = rem >> 6;
        int o = rem & 63;
        offw[i] = (kk * 256 + o0 + o) * 128 + cseg * 8;
    }

    // ---- MFMA fragment bases (ushort indices into LDS) ----
    int rr[7], wwv[7], bb[7];
#pragma unroll
    for (int f = 0; f < 7; ++f) {
        int s = wsd * 112 + f * 16 + l16;
        int r = s / 56;
        int w = s - r * 56;
        rr[f] = r; wwv[f] = w;
        bb[f] = (kgrp * 348 + r * 58 + w) * 8;
    }
    const int ab = (kgrp * 576 + wo * 32 + l16) * 8;

    f32x4 acc[2][7];
#pragma unroll
    for (int a = 0; a < 2; ++a)
#pragma unroll
        for (int f = 0; f < 7; ++f) acc[a][f] = (f32x4){0.f, 0.f, 0.f, 0.f};

    for (int c0 = 0; c0 < 128; c0 += 32) {
        // ---- DMA stage x tile ----
#pragma unroll
        for (int i = 0; i < 6; ++i) {
            if (vx[i])
                gload16(xpad + offx[i] + c0, &xs[(i * 256 + wave * 64) * 8]);
        }
        // ---- DMA stage weight tile ----
#pragma unroll
        for (int i = 0; i < 9; ++i)
            gload16(wq + offw[i] + c0, &wl[(i * 256 + wave * 64) * 8]);
        __syncthreads();

#pragma unroll
        for (int kk = 0; kk < 9; ++kk) {
            const int kh = kk / 3;
            const int kw = kk - kh * 3;
            s16x8 a0 = ldfrag(&wl[ab + kk * 512]);
            s16x8 a1 = ldfrag(&wl[ab + kk * 512 + 128]);
#pragma unroll
            for (int f = 0; f < 7; ++f) {
                s16x8 b = ldfrag(&xs[bb[f] + (kh * 58 + kw) * 8]);
                acc[0][f] = __builtin_amdgcn_mfma_f32_16x16x32_bf16(a0, b, acc[0][f], 0, 0, 0);
                acc[1][f] = __builtin_amdgcn_mfma_f32_16x16x32_bf16(a1, b, acc[1][f], 0, 0, 0);
            }
        }
        __syncthreads();
    }

    // ---- epilogue (identical mapping to verified round-1) ----
#pragma unroll
    for (int of = 0; of < 2; ++of) {
        int ob = o0 + wo * 32 + of * 16 + kgrp * 4;
#pragma unroll
        for (int f = 0; f < 7; ++f) {
            int h = h0 + rr[f];
            float* dst = out + ((size_t)(n * 256 + ob) * 56 + h) * 56 + wwv[f];
#pragma unroll
            for (int j = 0; j < 4; ++j) dst[(size_t)j * 3136] = acc[of][f][j];
        }
    }
}

// ---------------- fallback conv (round-1 verified) ----------------
__global__ __launch_bounds__(256) void conv_fb_k(const float* __restrict__ x,
                                                 const unsigned short* __restrict__ wq,
                                                 float* __restrict__ out) {
    __shared__ __align__(16) unsigned short xsf[6 * 58 * 40];
    __shared__ __align__(16) unsigned short wlf[9 * 64 * 40];

    const int tid = threadIdx.x;
    const int h0 = blockIdx.x * 4;
    const int n = blockIdx.y;
    const int o0 = blockIdx.z * 64;
    const int lane = tid & 63;
    const int wave = tid >> 6;
    const int wo = wave >> 1;
    const int wsd = wave & 1;
    const int l16 = lane & 15;
    const int kgrp = lane >> 4;

    int xb[7]; int rr[7]; int wwv[7];
#pragma unroll
    for (int f = 0; f < 7; ++f) {
        int s = wsd * 112 + f * 16 + l16;
        int r = s / 56;
        int w = s - r * 56;
        rr[f] = r; wwv[f] = w;
        xb[f] = (r * 58 + w) * 40 + kgrp * 8;
    }
    const int wa = (wo * 32 + l16) * 40 + kgrp * 8;

    f32x4 acc[2][7];
#pragma unroll
    for (int a = 0; a < 2; ++a)
#pragma unroll
        for (int f = 0; f < 7; ++f) acc[a][f] = (f32x4){0.f, 0.f, 0.f, 0.f};

    for (int c0 = 0; c0 < 128; c0 += 32) {
        for (int e = tid; e < 32 * 6 * 58; e += 256) {
            int c = e / 348;
            int rem = e - c * 348;
            int r = rem / 58;
            int col = rem - r * 58;
            int h = h0 - 1 + r;
            int w = col - 1;
            float val = 0.f;
            if ((unsigned)h < 56u && (unsigned)w < 56u)
                val = x[((size_t)(n * 128 + c0 + c) * 56 + h) * 56 + w];
            xsf[(r * 58 + col) * 40 + c] = f2bf(val);
        }
#pragma unroll
        for (int it = 0; it < 9; ++it) {
            int v = tid + it * 256;
            int cseg = v & 3;
            int o = (v >> 2) & 63;
            int kk = v >> 8;
            u16x8 dat = *(const u16x8*)(wq + (size_t)(kk * 256 + o0 + o) * 128 + c0 + cseg * 8);
            *(u16x8*)(&wlf[(kk * 64 + o) * 40 + cseg * 8]) = dat;
        }
        __syncthreads();
#pragma unroll
        for (int kk = 0; kk < 9; ++kk) {
            const int kh = kk / 3;
            const int kw = kk - kh * 3;
            s16x8 a0 = ldfrag(&wlf[kk * 2560 + wa]);
            s16x8 a1 = ldfrag(&wlf[kk * 2560 + wa + 640]);
            const int xoff = (kh * 58 + kw) * 40;
#pragma unroll
            for (int f = 0; f < 7; ++f) {
                s16x8 b = ldfrag(&xsf[xb[f] + xoff]);
                acc[0][f] = __builtin_amdgcn_mfma_f32_16x16x32_bf16(a0, b, acc[0][f], 0, 0, 0);
                acc[1][f] = __builtin_amdgcn_mfma_f32_16x16x32_bf16(a1, b, acc[1][f], 0, 0, 0);
            }
        }
        __syncthreads();
    }

#pragma unroll
    for (int of = 0; of < 2; ++of) {
        int ob = o0 + wo * 32 + of * 16 + kgrp * 4;
#pragma unroll
        for (int f = 0; f < 7; ++f) {
            int h = h0 + rr[f];
            float* dst = out + ((size_t)(n * 256 + ob) * 56 + h) * 56 + wwv[f];
#pragma unroll
            for (int j = 0; j < 4; ++j) dst[(size_t)j * 3136] = acc[of][f][j];
        }
    }
}

extern "C" void kernel_launch(void* const* d_in, const int* in_sizes, int n_in,
                              void* d_out, int out_size, void* d_ws, size_t ws_size,
                              hipStream_t stream) {
    const float* x = (const float*)d_in[0];
    const float* pc = (const float*)d_in[1];
    const float* ql = (const float*)d_in[2];
    float* out = (float*)d_out;

    if (ws_size >= XPAD_BYTES + WQ_BYTES) {
        unsigned short* xpad = (unsigned short*)d_ws;
        unsigned short* wq = (unsigned short*)((char*)d_ws + XPAD_BYTES);
        zero_k<<<1792, 256, 0, stream>>>((uint32_t*)xpad, (int)(XPAD_BYTES / 16));
        quant_k<<<1152, 256, 0, stream>>>(pc, ql, wq);
        xform_k<<<dim3(56, 32, 2), 256, 0, stream>>>(x, xpad);
        conv2_k<<<dim3(14, 32, 4), 256, 0, stream>>>(xpad, wq, out);
    } else {
        unsigned short* wq = (unsigned short*)d_ws;
        quant_k<<<1152, 256, 0, stream>>>(pc, ql, wq);
        conv_fb_k<<<dim3(14, 32, 4), 256, 0, stream>>>(x, wq, out);
    }
}